// Round 6
// baseline (400.162 us; speedup 1.0000x reference)
//
#include <hip/hip_runtime.h>
#include <stdint.h>

// Problem constants
#define BB 4
#define LL 2048
#define QQ 16293
#define RR 24
#define DD 32
#define SS 128
#define NLAYER 8
#define OUTW 1792
#define TT0 2047              // length of x after embedding (L-1)
#define MROWS (BB*OUTW)       // 7168
#define NPAD 16384            // padded Q for GEMM tiles
#define WCH 28                // skip rows per fused-layer block (64 blocks/batch)
#define NTILE 8               // n-tiles (128 cols) per GEMM block

typedef float v4f __attribute__((ext_vector_type(4)));
typedef short v8s __attribute__((ext_vector_type(8)));

static __device__ __forceinline__ unsigned short f2bf(float x) {
  unsigned int u = __float_as_uint(x);
  unsigned int r = (u + 0x7fffu + ((u >> 16) & 1u)) >> 16;
  return (unsigned short)r;
}

static __device__ __forceinline__ float fast_sigmoid(float z) {
  return __builtin_amdgcn_rcpf(1.0f + __expf(-z));
}
static __device__ __forceinline__ float fast_tanh(float z) {
  return 1.0f - 2.0f * __builtin_amdgcn_rcpf(1.0f + __expf(2.0f * z));
}

// ---------------------------------------------------------------------------
// Fused: embedding + 8 WaveNet layers + skip accumulation. (unchanged, ~25us)
// Grid (64, B), block 1024 = 16 waves.
// ---------------------------------------------------------------------------
__global__ __launch_bounds__(1024) void fused_layers_kernel(
    const int* __restrict__ idx, const float* __restrict__ preW,
    const float* __restrict__ filtW, const float* __restrict__ gateW,
    const float* __restrict__ resW, const float* __restrict__ skipW,
    float* __restrict__ skip_out) {
  int b = blockIdx.y;
  int j0 = blockIdx.x * WCH;
  int lane = (int)(threadIdx.x & 63);
  int w = __builtin_amdgcn_readfirstlane((int)(threadIdx.x >> 6));

  __shared__ float x_t[2][RR][66];   // col-major: x_t[buf][r][l]
  __shared__ float out_s[64][33];

  for (int z = (int)threadIdx.x; z < 2 * RR * 2; z += 1024) {
    int bu = z & 1;
    int cc = 64 + ((z >> 1) & 1);
    int r = z >> 2;
    x_t[bu][r][cc] = 0.f;
  }

  int tbase = j0 + 247;
  if (w < 12) {
    int t = tbase + lane;
    if (t > TT0 - 1) t = TT0 - 1;
    int i0 = idx[b * LL + t];
    int i1 = idx[b * LL + t + 1];
    const float* p0 = preW + (size_t)i0 * RR + 2 * w;
    const float* p1 = preW + (size_t)QQ * RR + (size_t)i1 * RR + 2 * w;
#pragma unroll
    for (int rr = 0; rr < 2; ++rr)
      x_t[0][2 * w + rr][lane] = p0[rr] + p1[rr];
  }

  float sk[8];
#pragma unroll
  for (int c = 0; c < 8; ++c) sk[c] = 0.f;

  __syncthreads();

  for (int i = 0; i < NLAYER; ++i) {
    int cur = i & 1, nxt = cur ^ 1;
    int lmax = 62 - i;

    float xa[RR], xb[RR];
#pragma unroll
    for (int r = 0; r < RR; ++r) {
      xa[r] = x_t[cur][r][lane];
      xb[r] = x_t[cur][r][lane + 1];
    }
    const float* Fw = filtW + (size_t)i * 2 * RR * DD;
    const float* Gw = gateW + (size_t)i * 2 * RR * DD;
    float zf[2], zg[2];
#pragma unroll
    for (int dd = 0; dd < 2; ++dd) { zf[dd] = 0.f; zg[dd] = 0.f; }
#pragma unroll
    for (int r = 0; r < RR; ++r) {
#pragma unroll
      for (int dd = 0; dd < 2; ++dd) {
        int d = w * 2 + dd;
        zf[dd] = fmaf(xa[r], Fw[r * DD + d], zf[dd]);
        zf[dd] = fmaf(xb[r], Fw[RR * DD + r * DD + d], zf[dd]);
        zg[dd] = fmaf(xa[r], Gw[r * DD + d], zg[dd]);
        zg[dd] = fmaf(xb[r], Gw[RR * DD + r * DD + d], zg[dd]);
      }
    }
    if (lane <= lmax) {
#pragma unroll
      for (int dd = 0; dd < 2; ++dd)
        out_s[lane][w * 2 + dd] = fast_tanh(zf[dd]) * fast_sigmoid(zg[dd]);
    }
    __syncthreads();

    if (lane < WCH) {
      const float* Sw = skipW + (size_t)i * DD * SS + w * 8;
#pragma unroll
      for (int d = 0; d < DD; ++d) {
        float o = out_s[lane + 7 - i][d];
#pragma unroll
        for (int c = 0; c < 8; ++c)
          sk[c] = fmaf(o, Sw[d * SS + c], sk[c]);
      }
    }

    if (w < 12 && lane <= lmax) {
      const float* Rw = resW + (size_t)i * DD * RR;
#pragma unroll
      for (int rr = 0; rr < 2; ++rr) {
        int r = w * 2 + rr;
        float acc = x_t[cur][r][lane + 1];
#pragma unroll
        for (int d = 0; d < DD; ++d)
          acc = fmaf(out_s[lane][d], Rw[d * RR + r], acc);
        x_t[nxt][r][lane] = acc;
      }
    }
    __syncthreads();
  }

  if (lane < WCH) {
    float* sp = skip_out + ((size_t)b * OUTW + j0 + lane) * SS + w * 8;
#pragma unroll
    for (int c4 = 0; c4 < 2; ++c4) {
      float4 v;
      v.x = sk[4 * c4 + 0]; v.y = sk[4 * c4 + 1];
      v.z = sk[4 * c4 + 2]; v.w = sk[4 * c4 + 3];
      *(float4*)(sp + 4 * c4) = v;
    }
  }
}

// ---------------------------------------------------------------------------
// h1 = relu(relu(skip_sum) @ post_W1), stored bf16  [7168][128] (unchanged)
// ---------------------------------------------------------------------------
__global__ __launch_bounds__(256) void h1_kernel(const float* __restrict__ skip_sum,
                                                 const float* __restrict__ W1,
                                                 unsigned short* __restrict__ h1) {
  int m0 = blockIdx.x * 32;
  int tc = threadIdx.x & 31;
  int tr = threadIdx.x >> 5;
  __shared__ float h_s[32][128];
#pragma unroll
  for (int it = 0; it < 16; ++it) {
    int lin = it * 256 + (int)threadIdx.x;
    int rrow = lin >> 7, d = lin & 127;
    float v = skip_sum[(size_t)(m0 + rrow) * SS + d];
    h_s[rrow][d] = v > 0.f ? v : 0.f;
  }
  __syncthreads();

  float acc[4][4];
#pragma unroll
  for (int rr = 0; rr < 4; ++rr)
#pragma unroll
    for (int c = 0; c < 4; ++c) acc[rr][c] = 0.f;

#pragma unroll 4
  for (int d = 0; d < 128; ++d) {
    float4 wv = *(const float4*)(W1 + (size_t)d * SS + tc * 4);
#pragma unroll
    for (int rr = 0; rr < 4; ++rr) {
      float hv = h_s[tr * 4 + rr][d];
      acc[rr][0] = fmaf(hv, wv.x, acc[rr][0]);
      acc[rr][1] = fmaf(hv, wv.y, acc[rr][1]);
      acc[rr][2] = fmaf(hv, wv.z, acc[rr][2]);
      acc[rr][3] = fmaf(hv, wv.w, acc[rr][3]);
    }
  }
#pragma unroll
  for (int rr = 0; rr < 4; ++rr) {
    int row = m0 + tr * 4 + rr;
    ushort4 u;
    u.x = f2bf(fmaxf(acc[rr][0], 0.f));
    u.y = f2bf(fmaxf(acc[rr][1], 0.f));
    u.z = f2bf(fmaxf(acc[rr][2], 0.f));
    u.w = f2bf(fmaxf(acc[rr][3], 0.f));
    *(ushort4*)(h1 + (size_t)row * SS + tc * 4) = u;
  }
}

// ---------------------------------------------------------------------------
// W2T: transpose post_W2 [128][16293] -> bf16 [16384][128], zero-padded
// ---------------------------------------------------------------------------
__global__ __launch_bounds__(256) void w2t_kernel(const float* __restrict__ W2,
                                                  unsigned short* __restrict__ W2T) {
  int n0 = blockIdx.x * 64;
  __shared__ float t_s[64][129];
#pragma unroll
  for (int it = 0; it < 32; ++it) {
    int lin = it * 256 + (int)threadIdx.x;
    int k = lin >> 6, nn = lin & 63;
    int n = n0 + nn;
    t_s[nn][k] = (n < QQ) ? W2[(size_t)k * QQ + n] : 0.f;
  }
  __syncthreads();
#pragma unroll
  for (int it = 0; it < 4; ++it) {
    int lin = it * 256 + (int)threadIdx.x;
    int nn = lin >> 4, slot = lin & 15;
    v8s val;
#pragma unroll
    for (int jj = 0; jj < 8; ++jj) val[jj] = (short)f2bf(t_s[nn][slot * 8 + jj]);
    *(v8s*)(W2T + ((size_t)(n0 + nn)) * 128 + slot * 8) = val;
  }
}

// ---------------------------------------------------------------------------
// logits = h1 @ W2  (bf16 MFMA, fp32 accum).  M=7168, N=16384(pad), K=128.
// v2: n-strip blocks. Grid (16,56); block = 128m x 1024n (8 tiles of 128).
// A fragments global->VGPR once (64 VGPR, K=128 fully resident);
// B fragments global->VGPR per tile (16B/lane, 4-lane line-coalesced);
// LDS only for C transpose [128][132]. Stores: per-row 16B-ALIGNED v4f
// (alignment shift a0 = (4 - m%4)&3 since QQ%4==1) + 4-scalar fringe lane,
// plain (L2-merged) stores, 4KB/row per block for HBM page locality.
// ---------------------------------------------------------------------------
__global__ __launch_bounds__(256) void gemm_kernel(const unsigned short* __restrict__ A,
                                                   const unsigned short* __restrict__ Bm,
                                                   float* __restrict__ Cc) {
  __shared__ float c_s[128][132];
  int m0 = blockIdx.y * 128;
  int n0 = blockIdx.x * (128 * NTILE);
  int tid = threadIdx.x;
  int lane = tid & 63;
  int w = tid >> 6;
  int wm = (w >> 1) * 64, wn = (w & 1) * 64;
  int lr = lane & 15, g = lane >> 4;

  // ---- A fragments, resident for whole block: [mf][ks]
  v8s afr[4][4];
#pragma unroll
  for (int mf = 0; mf < 4; ++mf)
#pragma unroll
    for (int ks = 0; ks < 4; ++ks)
      afr[mf][ks] = *(const v8s*)(A + ((size_t)(m0 + wm + mf * 16 + lr)) * 128 + (ks * 4 + g) * 8);

  int slot = tid & 31;            // store-phase column slot
  int rsub = tid >> 5;            // store-phase row sub-index (8 rows/iter)
  int am = rsub & 3;              // (m0+row)%4 == row%4 == rsub%4
  int a0 = (4 - am) & 3;          // first 16B-aligned float offset in tile

#pragma unroll 1
  for (int j = 0; j < NTILE; ++j) {
    int nb = n0 + j * 128;

    v4f acc[4][4];
#pragma unroll
    for (int mf = 0; mf < 4; ++mf)
#pragma unroll
      for (int nf = 0; nf < 4; ++nf) {
        v4f z = {0.f, 0.f, 0.f, 0.f};
        acc[mf][nf] = z;
      }

#pragma unroll
    for (int ks = 0; ks < 4; ++ks) {
      v8s bfr[4];
#pragma unroll
      for (int nf = 0; nf < 4; ++nf)
        bfr[nf] = *(const v8s*)(Bm + ((size_t)(nb + wn + nf * 16 + lr)) * 128 + (ks * 4 + g) * 8);
#pragma unroll
      for (int mf = 0; mf < 4; ++mf)
#pragma unroll
        for (int nf = 0; nf < 4; ++nf)
          acc[mf][nf] = __builtin_amdgcn_mfma_f32_16x16x32_bf16(afr[mf][ks], bfr[nf], acc[mf][nf], 0, 0, 0);
    }

    __syncthreads();   // c_s free (previous iter's readers done)
#pragma unroll
    for (int mf = 0; mf < 4; ++mf)
#pragma unroll
      for (int reg = 0; reg < 4; ++reg) {
        int row = wm + mf * 16 + g * 4 + reg;
#pragma unroll
        for (int nf = 0; nf < 4; ++nf)
          c_s[row][wn + nf * 16 + lr] = acc[mf][nf][reg];
      }
    __syncthreads();

    bool edge = (nb + 128 > QQ);
#pragma unroll
    for (int it = 0; it < 16; ++it) {
      int row = it * 8 + rsub;
      float* crow = Cc + (size_t)(m0 + row) * QQ;
      if (slot < 31) {
        int off = a0 + 4 * slot;
        int n = nb + off;
        v4f v;
        v[0] = c_s[row][off + 0];
        v[1] = c_s[row][off + 1];
        v[2] = c_s[row][off + 2];
        v[3] = c_s[row][off + 3];
        if (!edge) {
          *(v4f*)(crow + n) = v;              // 16B-aligned by construction
        } else if (n + 3 < QQ) {
          *(v4f*)(crow + n) = v;
        } else {
#pragma unroll
          for (int e = 0; e < 4; ++e)
            if (n + e < QQ) crow[n + e] = v[e];
        }
      } else {
        // fringe: tail [a0+124,128) plus head [0,a0)
#pragma unroll
        for (int e = 0; e < 4; ++e) {
          int col = (e < 4 - a0) ? (a0 + 124 + e) : (e - (4 - a0));
          int n = nb + col;
          if (!edge || n < QQ) crow[n] = c_s[row][col];
        }
      }
    }
  }
}

// ---------------------------------------------------------------------------
extern "C" void kernel_launch(void* const* d_in, const int* in_sizes, int n_in,
                              void* d_out, int out_size, void* d_ws, size_t ws_size,
                              hipStream_t stream) {
  (void)in_sizes; (void)n_in; (void)out_size; (void)ws_size;
  const int*   idx   = (const int*)d_in[0];
  const float* preW  = (const float*)d_in[1];
  const float* filtW = (const float*)d_in[2];
  const float* gateW = (const float*)d_in[3];
  const float* resW  = (const float*)d_in[4];
  const float* skipW = (const float*)d_in[5];
  const float* W1    = (const float*)d_in[6];
  const float* W2    = (const float*)d_in[7];
  float* out = (float*)d_out;

  char* ws = (char*)d_ws;
  float* skip = (float*)(ws);                              // 3,670,016 B
  unsigned short* h1  = (unsigned short*)(ws + 3670016);   // 1,835,008 B
  unsigned short* W2T = (unsigned short*)(ws + 5505024);   // 4,194,304 B  (~9.7 MB)

  w2t_kernel<<<dim3(NPAD / 64), 256, 0, stream>>>(W2, W2T);
  fused_layers_kernel<<<dim3(OUTW / WCH, BB), 1024, 0, stream>>>(idx, preW, filtW, gateW,
                                                                 resW, skipW, skip);
  h1_kernel<<<dim3(MROWS / 32), 256, 0, stream>>>(skip, W1, h1);
  gemm_kernel<<<dim3(NPAD / (128 * NTILE), MROWS / 128), 256, 0, stream>>>(h1, W2T, out);
}

// Round 7
// 340.136 us; speedup vs baseline: 1.1765x; 1.1765x over previous
//
#include <hip/hip_runtime.h>
#include <stdint.h>

// Problem constants
#define BB 4
#define LL 2048
#define QQ 16293
#define RR 24
#define DD 32
#define SS 128
#define NLAYER 8
#define OUTW 1792
#define TT0 2047              // length of x after embedding (L-1)
#define MROWS (BB*OUTW)       // 7168
#define NPAD 16384            // padded Q for GEMM tiles
#define WCH 28                // skip rows per fused-layer block (64 blocks/batch)

typedef float v4f __attribute__((ext_vector_type(4)));
typedef short v8s __attribute__((ext_vector_type(8)));

static __device__ __forceinline__ unsigned short f2bf(float x) {
  unsigned int u = __float_as_uint(x);
  unsigned int r = (u + 0x7fffu + ((u >> 16) & 1u)) >> 16;
  return (unsigned short)r;
}

static __device__ __forceinline__ float fast_sigmoid(float z) {
  return __builtin_amdgcn_rcpf(1.0f + __expf(-z));
}
static __device__ __forceinline__ float fast_tanh(float z) {
  return 1.0f - 2.0f * __builtin_amdgcn_rcpf(1.0f + __expf(2.0f * z));
}

// ---------------------------------------------------------------------------
// Fused: embedding + 8 WaveNet layers + skip accumulation. (unchanged, ~30us)
// Grid (64, B), block 1024 = 16 waves.
// ---------------------------------------------------------------------------
__global__ __launch_bounds__(1024) void fused_layers_kernel(
    const int* __restrict__ idx, const float* __restrict__ preW,
    const float* __restrict__ filtW, const float* __restrict__ gateW,
    const float* __restrict__ resW, const float* __restrict__ skipW,
    float* __restrict__ skip_out) {
  int b = blockIdx.y;
  int j0 = blockIdx.x * WCH;
  int lane = (int)(threadIdx.x & 63);
  int w = __builtin_amdgcn_readfirstlane((int)(threadIdx.x >> 6));

  __shared__ float x_t[2][RR][66];   // col-major: x_t[buf][r][l]
  __shared__ float out_s[64][33];

  for (int z = (int)threadIdx.x; z < 2 * RR * 2; z += 1024) {
    int bu = z & 1;
    int cc = 64 + ((z >> 1) & 1);
    int r = z >> 2;
    x_t[bu][r][cc] = 0.f;
  }

  int tbase = j0 + 247;
  if (w < 12) {
    int t = tbase + lane;
    if (t > TT0 - 1) t = TT0 - 1;
    int i0 = idx[b * LL + t];
    int i1 = idx[b * LL + t + 1];
    const float* p0 = preW + (size_t)i0 * RR + 2 * w;
    const float* p1 = preW + (size_t)QQ * RR + (size_t)i1 * RR + 2 * w;
#pragma unroll
    for (int rr = 0; rr < 2; ++rr)
      x_t[0][2 * w + rr][lane] = p0[rr] + p1[rr];
  }

  float sk[8];
#pragma unroll
  for (int c = 0; c < 8; ++c) sk[c] = 0.f;

  __syncthreads();

  for (int i = 0; i < NLAYER; ++i) {
    int cur = i & 1, nxt = cur ^ 1;
    int lmax = 62 - i;

    float xa[RR], xb[RR];
#pragma unroll
    for (int r = 0; r < RR; ++r) {
      xa[r] = x_t[cur][r][lane];
      xb[r] = x_t[cur][r][lane + 1];
    }
    const float* Fw = filtW + (size_t)i * 2 * RR * DD;
    const float* Gw = gateW + (size_t)i * 2 * RR * DD;
    float zf[2], zg[2];
#pragma unroll
    for (int dd = 0; dd < 2; ++dd) { zf[dd] = 0.f; zg[dd] = 0.f; }
#pragma unroll
    for (int r = 0; r < RR; ++r) {
#pragma unroll
      for (int dd = 0; dd < 2; ++dd) {
        int d = w * 2 + dd;
        zf[dd] = fmaf(xa[r], Fw[r * DD + d], zf[dd]);
        zf[dd] = fmaf(xb[r], Fw[RR * DD + r * DD + d], zf[dd]);
        zg[dd] = fmaf(xa[r], Gw[r * DD + d], zg[dd]);
        zg[dd] = fmaf(xb[r], Gw[RR * DD + r * DD + d], zg[dd]);
      }
    }
    if (lane <= lmax) {
#pragma unroll
      for (int dd = 0; dd < 2; ++dd)
        out_s[lane][w * 2 + dd] = fast_tanh(zf[dd]) * fast_sigmoid(zg[dd]);
    }
    __syncthreads();

    if (lane < WCH) {
      const float* Sw = skipW + (size_t)i * DD * SS + w * 8;
#pragma unroll
      for (int d = 0; d < DD; ++d) {
        float o = out_s[lane + 7 - i][d];
#pragma unroll
        for (int c = 0; c < 8; ++c)
          sk[c] = fmaf(o, Sw[d * SS + c], sk[c]);
      }
    }

    if (w < 12 && lane <= lmax) {
      const float* Rw = resW + (size_t)i * DD * RR;
#pragma unroll
      for (int rr = 0; rr < 2; ++rr) {
        int r = w * 2 + rr;
        float acc = x_t[cur][r][lane + 1];
#pragma unroll
        for (int d = 0; d < DD; ++d)
          acc = fmaf(out_s[lane][d], Rw[d * RR + r], acc);
        x_t[nxt][r][lane] = acc;
      }
    }
    __syncthreads();
  }

  if (lane < WCH) {
    float* sp = skip_out + ((size_t)b * OUTW + j0 + lane) * SS + w * 8;
#pragma unroll
    for (int c4 = 0; c4 < 2; ++c4) {
      float4 v;
      v.x = sk[4 * c4 + 0]; v.y = sk[4 * c4 + 1];
      v.z = sk[4 * c4 + 2]; v.w = sk[4 * c4 + 3];
      *(float4*)(sp + 4 * c4) = v;
    }
  }
}

// ---------------------------------------------------------------------------
// h1 = relu(relu(skip_sum) @ post_W1), stored bf16  [7168][128] (unchanged)
// ---------------------------------------------------------------------------
__global__ __launch_bounds__(256) void h1_kernel(const float* __restrict__ skip_sum,
                                                 const float* __restrict__ W1,
                                                 unsigned short* __restrict__ h1) {
  int m0 = blockIdx.x * 32;
  int tc = threadIdx.x & 31;
  int tr = threadIdx.x >> 5;
  __shared__ float h_s[32][128];
#pragma unroll
  for (int it = 0; it < 16; ++it) {
    int lin = it * 256 + (int)threadIdx.x;
    int rrow = lin >> 7, d = lin & 127;
    float v = skip_sum[(size_t)(m0 + rrow) * SS + d];
    h_s[rrow][d] = v > 0.f ? v : 0.f;
  }
  __syncthreads();

  float acc[4][4];
#pragma unroll
  for (int rr = 0; rr < 4; ++rr)
#pragma unroll
    for (int c = 0; c < 4; ++c) acc[rr][c] = 0.f;

#pragma unroll 4
  for (int d = 0; d < 128; ++d) {
    float4 wv = *(const float4*)(W1 + (size_t)d * SS + tc * 4);
#pragma unroll
    for (int rr = 0; rr < 4; ++rr) {
      float hv = h_s[tr * 4 + rr][d];
      acc[rr][0] = fmaf(hv, wv.x, acc[rr][0]);
      acc[rr][1] = fmaf(hv, wv.y, acc[rr][1]);
      acc[rr][2] = fmaf(hv, wv.z, acc[rr][2]);
      acc[rr][3] = fmaf(hv, wv.w, acc[rr][3]);
    }
  }
#pragma unroll
  for (int rr = 0; rr < 4; ++rr) {
    int row = m0 + tr * 4 + rr;
    ushort4 u;
    u.x = f2bf(fmaxf(acc[rr][0], 0.f));
    u.y = f2bf(fmaxf(acc[rr][1], 0.f));
    u.z = f2bf(fmaxf(acc[rr][2], 0.f));
    u.w = f2bf(fmaxf(acc[rr][3], 0.f));
    *(ushort4*)(h1 + (size_t)row * SS + tc * 4) = u;
  }
}

// ---------------------------------------------------------------------------
// W2T: transpose post_W2 [128][16293] -> bf16 [16384][128], zero-padded
// ---------------------------------------------------------------------------
__global__ __launch_bounds__(256) void w2t_kernel(const float* __restrict__ W2,
                                                  unsigned short* __restrict__ W2T) {
  int n0 = blockIdx.x * 64;
  __shared__ float t_s[64][129];
#pragma unroll
  for (int it = 0; it < 32; ++it) {
    int lin = it * 256 + (int)threadIdx.x;
    int k = lin >> 6, nn = lin & 63;
    int n = n0 + nn;
    t_s[nn][k] = (n < QQ) ? W2[(size_t)k * QQ + n] : 0.f;
  }
  __syncthreads();
#pragma unroll
  for (int it = 0; it < 4; ++it) {
    int lin = it * 256 + (int)threadIdx.x;
    int nn = lin >> 4, slot = lin & 15;
    v8s val;
#pragma unroll
    for (int jj = 0; jj < 8; ++jj) val[jj] = (short)f2bf(t_s[nn][slot * 8 + jj]);
    *(v8s*)(W2T + ((size_t)(n0 + nn)) * 128 + slot * 8) = val;
  }
}

// ---------------------------------------------------------------------------
// logits = h1 @ W2  (bf16 MFMA, fp32 accum).  M=7168, N=16384(pad), K=128.
// v3 = v1 block structure (128x128 tiles, LDS-staged A/B, LDS C transpose)
// with ONE change: stores are 16B-ALIGNED nontemporal v4f via per-row shift
// a0=(4-row%4)&3 (QQ%4==1 => row base misaligned by row%4 floats) + 4-scalar
// fringe lane. Theory: v1's misaligned nt 16B stores forced ECC RMW -> 2.1TB/s.
// ---------------------------------------------------------------------------
struct GemmLds {
  union {
    struct { unsigned short A_s[128 * 128]; unsigned short B_s[128 * 128]; } ab;
    float c_s[128][132];
  };
};

__global__ __launch_bounds__(256) void gemm_kernel(const unsigned short* __restrict__ A,
                                                   const unsigned short* __restrict__ Bm,
                                                   float* __restrict__ Cc) {
  __shared__ GemmLds sh;
  unsigned short* A_s = sh.ab.A_s;
  unsigned short* B_s = sh.ab.B_s;
  int m0 = blockIdx.y * 128;
  int n0 = blockIdx.x * 128;
  int tid = threadIdx.x;

#pragma unroll
  for (int it = 0; it < 8; ++it) {
    int lin = it * 256 + tid;
    int row = lin >> 4, slot = lin & 15;
    int sw = slot ^ (row & 7);
    uint4 va = *(const uint4*)(A + ((size_t)(m0 + row)) * 128 + slot * 8);
    *(uint4*)(A_s + row * 128 + sw * 8) = va;
    uint4 vb = *(const uint4*)(Bm + ((size_t)(n0 + row)) * 128 + slot * 8);
    *(uint4*)(B_s + row * 128 + sw * 8) = vb;
  }
  __syncthreads();

  int lane = tid & 63;
  int w = tid >> 6;
  int wm = (w >> 1) * 64, wn = (w & 1) * 64;
  int lr = lane & 15, g = lane >> 4;

  v4f acc[4][4];
#pragma unroll
  for (int mf = 0; mf < 4; ++mf)
#pragma unroll
    for (int nf = 0; nf < 4; ++nf) {
      v4f z = {0.f, 0.f, 0.f, 0.f};
      acc[mf][nf] = z;
    }

#pragma unroll
  for (int ks = 0; ks < 4; ++ks) {
    int kg = ks * 4 + g;
    v8s a[4], bfr[4];
#pragma unroll
    for (int mf = 0; mf < 4; ++mf) {
      int row = wm + mf * 16 + lr;
      a[mf] = *(v8s*)(A_s + row * 128 + ((kg ^ (row & 7)) * 8));
    }
#pragma unroll
    for (int nf = 0; nf < 4; ++nf) {
      int row = wn + nf * 16 + lr;
      bfr[nf] = *(v8s*)(B_s + row * 128 + ((kg ^ (row & 7)) * 8));
    }
#pragma unroll
    for (int mf = 0; mf < 4; ++mf)
#pragma unroll
      for (int nf = 0; nf < 4; ++nf)
        acc[mf][nf] = __builtin_amdgcn_mfma_f32_16x16x32_bf16(a[mf], bfr[nf], acc[mf][nf], 0, 0, 0);
  }

  // ---- epilogue: acc -> LDS transpose, then ALIGNED nt stores
  __syncthreads();   // all LDS reads of A_s/B_s done
#pragma unroll
  for (int mf = 0; mf < 4; ++mf)
#pragma unroll
    for (int reg = 0; reg < 4; ++reg) {
      int row = wm + mf * 16 + g * 4 + reg;
#pragma unroll
      for (int nf = 0; nf < 4; ++nf)
        sh.c_s[row][wn + nf * 16 + lr] = acc[mf][nf][reg];
    }
  __syncthreads();

  int slot = tid & 31;            // 31 vector slots + 1 fringe slot per row
  int rsub = tid >> 5;            // 8 rows per iteration
  int a0 = (4 - (rsub & 3)) & 3;  // (m0+row)%4 == rsub%4 -> first aligned col
  bool edge = (n0 + 128 > QQ);
#pragma unroll
  for (int it = 0; it < 16; ++it) {
    int row = it * 8 + rsub;
    float* crow = Cc + (size_t)(m0 + row) * QQ;
    if (slot < 31) {
      int off = a0 + 4 * slot;
      int n = n0 + off;
      v4f v;
      v[0] = sh.c_s[row][off + 0];
      v[1] = sh.c_s[row][off + 1];
      v[2] = sh.c_s[row][off + 2];
      v[3] = sh.c_s[row][off + 3];
      if (!edge) {
        __builtin_nontemporal_store(v, (v4f*)(crow + n));   // 16B-aligned
      } else if (n + 3 < QQ) {
        __builtin_nontemporal_store(v, (v4f*)(crow + n));
      } else {
#pragma unroll
        for (int e = 0; e < 4; ++e)
          if (n + e < QQ) crow[n + e] = v[e];
      }
    } else {
      // fringe: tail [a0+124,128) then head [0,a0)
#pragma unroll
      for (int e = 0; e < 4; ++e) {
        int col = (e < 4 - a0) ? (a0 + 124 + e) : (e - (4 - a0));
        int n = n0 + col;
        if (!edge || n < QQ) crow[n] = sh.c_s[row][col];
      }
    }
  }
}

// ---------------------------------------------------------------------------
extern "C" void kernel_launch(void* const* d_in, const int* in_sizes, int n_in,
                              void* d_out, int out_size, void* d_ws, size_t ws_size,
                              hipStream_t stream) {
  (void)in_sizes; (void)n_in; (void)out_size; (void)ws_size;
  const int*   idx   = (const int*)d_in[0];
  const float* preW  = (const float*)d_in[1];
  const float* filtW = (const float*)d_in[2];
  const float* gateW = (const float*)d_in[3];
  const float* resW  = (const float*)d_in[4];
  const float* skipW = (const float*)d_in[5];
  const float* W1    = (const float*)d_in[6];
  const float* W2    = (const float*)d_in[7];
  float* out = (float*)d_out;

  char* ws = (char*)d_ws;
  float* skip = (float*)(ws);                              // 3,670,016 B
  unsigned short* h1  = (unsigned short*)(ws + 3670016);   // 1,835,008 B
  unsigned short* W2T = (unsigned short*)(ws + 5505024);   // 4,194,304 B  (~9.7 MB)

  w2t_kernel<<<dim3(NPAD / 64), 256, 0, stream>>>(W2, W2T);
  fused_layers_kernel<<<dim3(OUTW / WCH, BB), 1024, 0, stream>>>(idx, preW, filtW, gateW,
                                                                 resW, skipW, skip);
  h1_kernel<<<dim3(MROWS / 32), 256, 0, stream>>>(skip, W1, h1);
  gemm_kernel<<<dim3(NPAD / 128, MROWS / 128), 256, 0, stream>>>(h1, W2T, out);
}

// Round 8
// 316.497 us; speedup vs baseline: 1.2643x; 1.0747x over previous
//
#include <hip/hip_runtime.h>
#include <stdint.h>

// Problem constants
#define BB 4
#define LL 2048
#define QQ 16293
#define RR 24
#define DD 32
#define SS 128
#define NLAYER 8
#define OUTW 1792
#define TT0 2047              // length of x after embedding (L-1)
#define MROWS (BB*OUTW)       // 7168
#define NPAD 16384            // padded Q for GEMM tiles
#define WCH 28                // skip rows per fused-layer block (64 blocks/batch)

typedef float v4f __attribute__((ext_vector_type(4)));
typedef short v8s __attribute__((ext_vector_type(8)));

static __device__ __forceinline__ unsigned short f2bf(float x) {
  unsigned int u = __float_as_uint(x);
  unsigned int r = (u + 0x7fffu + ((u >> 16) & 1u)) >> 16;
  return (unsigned short)r;
}

static __device__ __forceinline__ float fast_sigmoid(float z) {
  return __builtin_amdgcn_rcpf(1.0f + __expf(-z));
}
static __device__ __forceinline__ float fast_tanh(float z) {
  return 1.0f - 2.0f * __builtin_amdgcn_rcpf(1.0f + __expf(2.0f * z));
}

// ---------------------------------------------------------------------------
// Fused: embedding + 8 WaveNet layers + skip accumulation. (unchanged)
// Grid (64, B), block 1024 = 16 waves.
// ---------------------------------------------------------------------------
__global__ __launch_bounds__(1024) void fused_layers_kernel(
    const int* __restrict__ idx, const float* __restrict__ preW,
    const float* __restrict__ filtW, const float* __restrict__ gateW,
    const float* __restrict__ resW, const float* __restrict__ skipW,
    float* __restrict__ skip_out) {
  int b = blockIdx.y;
  int j0 = blockIdx.x * WCH;
  int lane = (int)(threadIdx.x & 63);
  int w = __builtin_amdgcn_readfirstlane((int)(threadIdx.x >> 6));

  __shared__ float x_t[2][RR][66];   // col-major: x_t[buf][r][l]
  __shared__ float out_s[64][33];

  for (int z = (int)threadIdx.x; z < 2 * RR * 2; z += 1024) {
    int bu = z & 1;
    int cc = 64 + ((z >> 1) & 1);
    int r = z >> 2;
    x_t[bu][r][cc] = 0.f;
  }

  int tbase = j0 + 247;
  if (w < 12) {
    int t = tbase + lane;
    if (t > TT0 - 1) t = TT0 - 1;
    int i0 = idx[b * LL + t];
    int i1 = idx[b * LL + t + 1];
    const float* p0 = preW + (size_t)i0 * RR + 2 * w;
    const float* p1 = preW + (size_t)QQ * RR + (size_t)i1 * RR + 2 * w;
#pragma unroll
    for (int rr = 0; rr < 2; ++rr)
      x_t[0][2 * w + rr][lane] = p0[rr] + p1[rr];
  }

  float sk[8];
#pragma unroll
  for (int c = 0; c < 8; ++c) sk[c] = 0.f;

  __syncthreads();

  for (int i = 0; i < NLAYER; ++i) {
    int cur = i & 1, nxt = cur ^ 1;
    int lmax = 62 - i;

    float xa[RR], xb[RR];
#pragma unroll
    for (int r = 0; r < RR; ++r) {
      xa[r] = x_t[cur][r][lane];
      xb[r] = x_t[cur][r][lane + 1];
    }
    const float* Fw = filtW + (size_t)i * 2 * RR * DD;
    const float* Gw = gateW + (size_t)i * 2 * RR * DD;
    float zf[2], zg[2];
#pragma unroll
    for (int dd = 0; dd < 2; ++dd) { zf[dd] = 0.f; zg[dd] = 0.f; }
#pragma unroll
    for (int r = 0; r < RR; ++r) {
#pragma unroll
      for (int dd = 0; dd < 2; ++dd) {
        int d = w * 2 + dd;
        zf[dd] = fmaf(xa[r], Fw[r * DD + d], zf[dd]);
        zf[dd] = fmaf(xb[r], Fw[RR * DD + r * DD + d], zf[dd]);
        zg[dd] = fmaf(xa[r], Gw[r * DD + d], zg[dd]);
        zg[dd] = fmaf(xb[r], Gw[RR * DD + r * DD + d], zg[dd]);
      }
    }
    if (lane <= lmax) {
#pragma unroll
      for (int dd = 0; dd < 2; ++dd)
        out_s[lane][w * 2 + dd] = fast_tanh(zf[dd]) * fast_sigmoid(zg[dd]);
    }
    __syncthreads();

    if (lane < WCH) {
      const float* Sw = skipW + (size_t)i * DD * SS + w * 8;
#pragma unroll
      for (int d = 0; d < DD; ++d) {
        float o = out_s[lane + 7 - i][d];
#pragma unroll
        for (int c = 0; c < 8; ++c)
          sk[c] = fmaf(o, Sw[d * SS + c], sk[c]);
      }
    }

    if (w < 12 && lane <= lmax) {
      const float* Rw = resW + (size_t)i * DD * RR;
#pragma unroll
      for (int rr = 0; rr < 2; ++rr) {
        int r = w * 2 + rr;
        float acc = x_t[cur][r][lane + 1];
#pragma unroll
        for (int d = 0; d < DD; ++d)
          acc = fmaf(out_s[lane][d], Rw[d * RR + r], acc);
        x_t[nxt][r][lane] = acc;
      }
    }
    __syncthreads();
  }

  if (lane < WCH) {
    float* sp = skip_out + ((size_t)b * OUTW + j0 + lane) * SS + w * 8;
#pragma unroll
    for (int c4 = 0; c4 < 2; ++c4) {
      float4 v;
      v.x = sk[4 * c4 + 0]; v.y = sk[4 * c4 + 1];
      v.z = sk[4 * c4 + 2]; v.w = sk[4 * c4 + 3];
      *(float4*)(sp + 4 * c4) = v;
    }
  }
}

// ---------------------------------------------------------------------------
// h1 = relu(relu(skip_sum) @ post_W1), stored bf16  [7168][128] (unchanged)
// ---------------------------------------------------------------------------
__global__ __launch_bounds__(256) void h1_kernel(const float* __restrict__ skip_sum,
                                                 const float* __restrict__ W1,
                                                 unsigned short* __restrict__ h1) {
  int m0 = blockIdx.x * 32;
  int tc = threadIdx.x & 31;
  int tr = threadIdx.x >> 5;
  __shared__ float h_s[32][128];
#pragma unroll
  for (int it = 0; it < 16; ++it) {
    int lin = it * 256 + (int)threadIdx.x;
    int rrow = lin >> 7, d = lin & 127;
    float v = skip_sum[(size_t)(m0 + rrow) * SS + d];
    h_s[rrow][d] = v > 0.f ? v : 0.f;
  }
  __syncthreads();

  float acc[4][4];
#pragma unroll
  for (int rr = 0; rr < 4; ++rr)
#pragma unroll
    for (int c = 0; c < 4; ++c) acc[rr][c] = 0.f;

#pragma unroll 4
  for (int d = 0; d < 128; ++d) {
    float4 wv = *(const float4*)(W1 + (size_t)d * SS + tc * 4);
#pragma unroll
    for (int rr = 0; rr < 4; ++rr) {
      float hv = h_s[tr * 4 + rr][d];
      acc[rr][0] = fmaf(hv, wv.x, acc[rr][0]);
      acc[rr][1] = fmaf(hv, wv.y, acc[rr][1]);
      acc[rr][2] = fmaf(hv, wv.z, acc[rr][2]);
      acc[rr][3] = fmaf(hv, wv.w, acc[rr][3]);
    }
  }
#pragma unroll
  for (int rr = 0; rr < 4; ++rr) {
    int row = m0 + tr * 4 + rr;
    ushort4 u;
    u.x = f2bf(fmaxf(acc[rr][0], 0.f));
    u.y = f2bf(fmaxf(acc[rr][1], 0.f));
    u.z = f2bf(fmaxf(acc[rr][2], 0.f));
    u.w = f2bf(fmaxf(acc[rr][3], 0.f));
    *(ushort4*)(h1 + (size_t)row * SS + tc * 4) = u;
  }
}

// ---------------------------------------------------------------------------
// W2T: transpose post_W2 [128][16293] -> bf16 [16384][128], zero-padded
// ---------------------------------------------------------------------------
__global__ __launch_bounds__(256) void w2t_kernel(const float* __restrict__ W2,
                                                  unsigned short* __restrict__ W2T) {
  int n0 = blockIdx.x * 64;
  __shared__ float t_s[64][129];
#pragma unroll
  for (int it = 0; it < 32; ++it) {
    int lin = it * 256 + (int)threadIdx.x;
    int k = lin >> 6, nn = lin & 63;
    int n = n0 + nn;
    t_s[nn][k] = (n < QQ) ? W2[(size_t)k * QQ + n] : 0.f;
  }
  __syncthreads();
#pragma unroll
  for (int it = 0; it < 4; ++it) {
    int lin = it * 256 + (int)threadIdx.x;
    int nn = lin >> 4, slot = lin & 15;
    v8s val;
#pragma unroll
    for (int jj = 0; jj < 8; ++jj) val[jj] = (short)f2bf(t_s[nn][slot * 8 + jj]);
    *(v8s*)(W2T + ((size_t)(n0 + nn)) * 128 + slot * 8) = val;
  }
}

// ---------------------------------------------------------------------------
// logits = h1 @ W2  (bf16 MFMA, fp32 accum).  M=7168, N=16384(pad), K=128.
// v4 = v1 block structure (128x128 tiles, LDS-staged A/B, LDS C transpose)
// with the store loop replaced by the FILL-KERNEL pattern (the only store
// shape measured at 6.8 TB/s on this buffer): plain dword stores, each wave
// one contiguous 256B run, 2 rows x 128 cols per iteration, no nt, no fringe.
// ---------------------------------------------------------------------------
struct GemmLds {
  union {
    struct { unsigned short A_s[128 * 128]; unsigned short B_s[128 * 128]; } ab;
    float c_s[128][132];
  };
};

__global__ __launch_bounds__(256) void gemm_kernel(const unsigned short* __restrict__ A,
                                                   const unsigned short* __restrict__ Bm,
                                                   float* __restrict__ Cc) {
  __shared__ GemmLds sh;
  unsigned short* A_s = sh.ab.A_s;
  unsigned short* B_s = sh.ab.B_s;
  int m0 = blockIdx.y * 128;
  int n0 = blockIdx.x * 128;
  int tid = threadIdx.x;

#pragma unroll
  for (int it = 0; it < 8; ++it) {
    int lin = it * 256 + tid;
    int row = lin >> 4, slot = lin & 15;
    int sw = slot ^ (row & 7);
    uint4 va = *(const uint4*)(A + ((size_t)(m0 + row)) * 128 + slot * 8);
    *(uint4*)(A_s + row * 128 + sw * 8) = va;
    uint4 vb = *(const uint4*)(Bm + ((size_t)(n0 + row)) * 128 + slot * 8);
    *(uint4*)(B_s + row * 128 + sw * 8) = vb;
  }
  __syncthreads();

  int lane = tid & 63;
  int w = tid >> 6;
  int wm = (w >> 1) * 64, wn = (w & 1) * 64;
  int lr = lane & 15, g = lane >> 4;

  v4f acc[4][4];
#pragma unroll
  for (int mf = 0; mf < 4; ++mf)
#pragma unroll
    for (int nf = 0; nf < 4; ++nf) {
      v4f z = {0.f, 0.f, 0.f, 0.f};
      acc[mf][nf] = z;
    }

#pragma unroll
  for (int ks = 0; ks < 4; ++ks) {
    int kg = ks * 4 + g;
    v8s a[4], bfr[4];
#pragma unroll
    for (int mf = 0; mf < 4; ++mf) {
      int row = wm + mf * 16 + lr;
      a[mf] = *(v8s*)(A_s + row * 128 + ((kg ^ (row & 7)) * 8));
    }
#pragma unroll
    for (int nf = 0; nf < 4; ++nf) {
      int row = wn + nf * 16 + lr;
      bfr[nf] = *(v8s*)(B_s + row * 128 + ((kg ^ (row & 7)) * 8));
    }
#pragma unroll
    for (int mf = 0; mf < 4; ++mf)
#pragma unroll
      for (int nf = 0; nf < 4; ++nf)
        acc[mf][nf] = __builtin_amdgcn_mfma_f32_16x16x32_bf16(a[mf], bfr[nf], acc[mf][nf], 0, 0, 0);
  }

  // ---- epilogue: acc -> LDS transpose, then fill-pattern dword stores
  __syncthreads();   // all LDS reads of A_s/B_s done
#pragma unroll
  for (int mf = 0; mf < 4; ++mf)
#pragma unroll
    for (int reg = 0; reg < 4; ++reg) {
      int row = wm + mf * 16 + g * 4 + reg;
#pragma unroll
      for (int nf = 0; nf < 4; ++nf)
        sh.c_s[row][wn + nf * 16 + lr] = acc[mf][nf][reg];
    }
  __syncthreads();

  bool edge = (n0 + 128 > QQ);
  int col = tid & 127;            // wave = 64 consecutive cols -> 256B run
  int r0 = tid >> 7;              // 2 rows per iteration
  int n = n0 + col;
  if (!edge) {
#pragma unroll
    for (int it = 0; it < 64; ++it) {
      int row = it * 2 + r0;
      Cc[(size_t)(m0 + row) * QQ + n] = sh.c_s[row][col];
    }
  } else {
    bool ok = n < QQ;
#pragma unroll
    for (int it = 0; it < 64; ++it) {
      int row = it * 2 + r0;
      if (ok) Cc[(size_t)(m0 + row) * QQ + n] = sh.c_s[row][col];
    }
  }
}

// ---------------------------------------------------------------------------
extern "C" void kernel_launch(void* const* d_in, const int* in_sizes, int n_in,
                              void* d_out, int out_size, void* d_ws, size_t ws_size,
                              hipStream_t stream) {
  (void)in_sizes; (void)n_in; (void)out_size; (void)ws_size;
  const int*   idx   = (const int*)d_in[0];
  const float* preW  = (const float*)d_in[1];
  const float* filtW = (const float*)d_in[2];
  const float* gateW = (const float*)d_in[3];
  const float* resW  = (const float*)d_in[4];
  const float* skipW = (const float*)d_in[5];
  const float* W1    = (const float*)d_in[6];
  const float* W2    = (const float*)d_in[7];
  float* out = (float*)d_out;

  char* ws = (char*)d_ws;
  float* skip = (float*)(ws);                              // 3,670,016 B
  unsigned short* h1  = (unsigned short*)(ws + 3670016);   // 1,835,008 B
  unsigned short* W2T = (unsigned short*)(ws + 5505024);   // 4,194,304 B  (~9.7 MB)

  w2t_kernel<<<dim3(NPAD / 64), 256, 0, stream>>>(W2, W2T);
  fused_layers_kernel<<<dim3(OUTW / WCH, BB), 1024, 0, stream>>>(idx, preW, filtW, gateW,
                                                                 resW, skipW, skip);
  h1_kernel<<<dim3(MROWS / 32), 256, 0, stream>>>(skip, W1, h1);
  gemm_kernel<<<dim3(NPAD / 128, MROWS / 128), 256, 0, stream>>>(h1, W2T, out);
}